// Round 1
// 560.817 us; speedup vs baseline: 1.0654x; 1.0654x over previous
//
#include <hip/hip_runtime.h>

// DeepSNNController: 3-layer LIF SNN, T=100, B=4096, 9 -> 96 -> 96 -> 48.
//
// R9 "register-weights" rewrite. Diagnosis of the 596µs P7 kernel: LDS
// instruction-throughput bound (216 ds_read_b128/thread/t re-reading the SAME
// W2/W3 every timestep; 864 b128/CU/t x ~12cyc ~= the whole 12.5k cyc/t wall)
// at 1 wave/SIMD occupancy. Fix: all weights live in REGISTERS for the whole
// kernel; only 0/1 spikes cross LDS.
//
// Exactness (absmax must stay 0): the P7 add order is preserved bit-for-bit.
//   dot(K): mod-4 k-split, ascending within residue, combined (r0+r1)+(r2+r3).
// Lane r of each 4-lane quad owns residue class r and computes the IDENTICAL
// fmaf chain the P7 kernel computed as c[r]; the pair tree is done with
// quad-perm DPP adds (IEEE fadd is bitwise-commutative, so all 4 lanes get
// identical bits). L1 (K=9) stays whole-dot-per-thread: literally P7's code.
// All products are exact (spikes/inputs in {0,1}), LIF op order unchanged:
//   mn = ((0.92*mp) + (dot + b)) - reset.
//
// Layout: block = 192 threads = 48 quads; (v = tid>>2, r = tid&3).
//   L2: lane owns neurons {v, v+48}, residue r  -> w2[2][24] regs
//   L3: lane owns neuron v, residue r           -> w3[24] regs
//   L1: thread (n1 = tid>>1, bh = tid&1) owns neuron n1 for 2 batches -> w1[9]
// NB=4 batches/block, grid=1024 -> 4 blocks/CU, 12 waves/CU (vs 4 before).
// Spikes: residue-major bytes s*r[b][r][32]; lane reads its 24 bytes as
// b128+b64 (4 distinct addresses/wave -> pure broadcast, conflict-free).
// x(t+1) is register-prefetched during t so its latency hides under L2/L3.

constexpr int T_STEPS = 100;
constexpr int BATCH   = 4096;
constexpr int D_INP   = 9;
constexpr int H       = 96;
constexpr int H3      = 48;
constexpr int NB      = 4;     // batch elements per block
constexpr int BLOCK   = 192;   // 48 quads

__device__ __forceinline__ float lif_step(float sum, float bias, float& m) {
    const float cur   = __fadd_rn(sum, bias);
    const float mp    = m;
    const float reset = (mp > 1.0f) ? 1.0f : 0.0f;
    const float mn    = __fsub_rn(__fadd_rn(__fmul_rn(0.92f, mp), cur), reset);
    m = mn;
    return mn;
}

#if defined(__has_builtin)
#if __has_builtin(__builtin_amdgcn_mov_dpp)
#define SNN_HAS_DPP 1
#endif
#endif

// Exchange-and-add across the quad. CTRL=0xB1: quad_perm [1,0,3,2] (xor 1);
// CTRL=0x4E: quad_perm [2,3,0,1] (xor 2). fadd(a,b)==fadd(b,a) bitwise, so
// every lane of the quad ends with identical bits.
template <int CTRL>
__device__ __forceinline__ float xadd(float c) {
#ifdef SNN_HAS_DPP
    const int o = __builtin_amdgcn_mov_dpp(__float_as_int(c), CTRL, 0xF, 0xF, false);
    return __fadd_rn(c, __int_as_float(o));
#else
    return __fadd_rn(c, __shfl_xor(c, (CTRL == 0xB1) ? 1 : 2, 64));
#endif
}

// lanes r=0..3 hold P7 residue partials c_r; returns (c0+c1)+(c2+c3) in ALL lanes.
__device__ __forceinline__ float quad_red(float c) {
    return xadd<0x4E>(xadd<0xB1>(c));
}

// Unpack one dword of 4 spike bytes (values 0/1 -> cvt exact) and advance the
// two L2 fmaf chains in ascending-j (== ascending-k-within-residue) P7 order.
#define L2_DW(dw, JB)                                                         \
    {                                                                         \
        const unsigned _u = (dw);                                             \
        const float _s0 = (float)( _u        & 255u);                         \
        const float _s1 = (float)((_u >> 8)  & 255u);                         \
        const float _s2 = (float)((_u >> 16) & 255u);                         \
        const float _s3 = (float)( _u >> 24);                                 \
        cA = fmaf(w2[0][(JB)+0], _s0, cA); cB = fmaf(w2[1][(JB)+0], _s0, cB); \
        cA = fmaf(w2[0][(JB)+1], _s1, cA); cB = fmaf(w2[1][(JB)+1], _s1, cB); \
        cA = fmaf(w2[0][(JB)+2], _s2, cA); cB = fmaf(w2[1][(JB)+2], _s2, cB); \
        cA = fmaf(w2[0][(JB)+3], _s3, cA); cB = fmaf(w2[1][(JB)+3], _s3, cB); \
    }

#define L3_DW(dw, JB)                                                         \
    {                                                                         \
        const unsigned _u = (dw);                                             \
        const float _s0 = (float)( _u        & 255u);                         \
        const float _s1 = (float)((_u >> 8)  & 255u);                         \
        const float _s2 = (float)((_u >> 16) & 255u);                         \
        const float _s3 = (float)( _u >> 24);                                 \
        c = fmaf(w3[(JB)+0], _s0, c);                                         \
        c = fmaf(w3[(JB)+1], _s1, c);                                         \
        c = fmaf(w3[(JB)+2], _s2, c);                                         \
        c = fmaf(w3[(JB)+3], _s3, c);                                         \
    }

__global__ __launch_bounds__(BLOCK, 3)
void snn_rw(const float* __restrict__ x,
            const float* __restrict__ W1g, const float* __restrict__ b1g,
            const float* __restrict__ W2g, const float* __restrict__ b2g,
            const float* __restrict__ W3g, const float* __restrict__ b3g,
            float* __restrict__ out)
{
    // spike(n) lives at [b][n&3][n>>2]; rows padded to 32 B so lane reads are
    // 16B-aligned. Total LDS = 2 * 4*4*32 = 1024 B -> occupancy unconstrained.
    __shared__ __align__(16) unsigned char s1r[NB][4][32];
    __shared__ __align__(16) unsigned char s2r[NB][4][32];

    const int tid = threadIdx.x;
    const int v   = tid >> 2;   // quad id 0..47
    const int r   = tid & 3;    // k residue class
    const int n1  = tid >> 1;   // L1 neuron 0..95
    const int bh  = tid & 1;    // L1 batch half
    const int bg0 = blockIdx.x * NB;

    // ---- weights -> registers (read once, reused all 100 timesteps) ----
    float w2[2][24], w3[24], w1[D_INP];
    #pragma unroll
    for (int j = 0; j < 24; ++j) {
        w2[0][j] = W2g[(v     ) * H + 4 * j + r];
        w2[1][j] = W2g[(v + 48) * H + 4 * j + r];
        w3[j]    = W3g[(v     ) * H + 4 * j + r];
    }
    #pragma unroll
    for (int k = 0; k < D_INP; ++k) w1[k] = W1g[n1 * D_INP + k];
    const float bb1  = b1g[n1];
    const float bb2A = b2g[v];
    const float bb2B = b2g[v + 48];
    const float bb3  = b3g[v];

    float m1[2]   = {0.f, 0.f};
    float m2A[NB] = {}, m2B[NB] = {}, m3[NB] = {};

    // prologue: x(0) into registers
    float xr[2][D_INP];
    #pragma unroll
    for (int bi = 0; bi < 2; ++bi) {
        const size_t xb = ((size_t)0 * BATCH + bg0 + 2 * bh + bi) * D_INP;
        #pragma unroll
        for (int k = 0; k < D_INP; ++k) xr[bi][k] = x[xb + k];
    }

    float* out_spk = out;
    float* out_mem = out + (size_t)T_STEPS * BATCH * H3;

    for (int t = 0; t < T_STEPS; ++t) {
        // ---- layer 1: 9 -> 96, whole dot per thread, P7 order verbatim ----
        #pragma unroll
        for (int bi = 0; bi < 2; ++bi) {
            const int b = 2 * bh + bi;
            float q[D_INP];
            #pragma unroll
            for (int k = 0; k < D_INP; ++k) q[k] = __fmul_rn(w1[k], xr[bi][k]); // exact
            const float r0 = __fadd_rn(__fadd_rn(q[8], q[0]), q[4]);
            const float r1 = __fadd_rn(q[1], q[5]);
            const float r2 = __fadd_rn(q[2], q[6]);
            const float r3 = __fadd_rn(q[3], q[7]);
            const float s  = __fadd_rn(__fadd_rn(r0, r1), __fadd_rn(r2, r3));
            const float mn = lif_step(s, bb1, m1[bi]);
            s1r[b][n1 & 3][n1 >> 2] = (mn > 1.0f) ? (unsigned char)1 : (unsigned char)0;
        }
        // register-prefetch x(t+1); consumed next iteration, latency hides
        // under L2/L3 compute of this iteration.
        if (t + 1 < T_STEPS) {
            #pragma unroll
            for (int bi = 0; bi < 2; ++bi) {
                const size_t xb = ((size_t)(t + 1) * BATCH + bg0 + 2 * bh + bi) * D_INP;
                #pragma unroll
                for (int k = 0; k < D_INP; ++k) xr[bi][k] = x[xb + k];
            }
        }
        __syncthreads();   // B: s1r visible

        // ---- layer 2: 96 -> 96, residue chains == P7's c[r], DPP combine ----
        #pragma unroll
        for (int b = 0; b < NB; ++b) {
            const uint4 u0 = *(const uint4*)&s1r[b][r][0];   // 4 distinct addrs/wave: broadcast
            const uint2 u1 = *(const uint2*)&s1r[b][r][16];
            float cA = 0.f, cB = 0.f;
            L2_DW(u0.x,  0) L2_DW(u0.y,  4) L2_DW(u0.z,  8) L2_DW(u0.w, 12)
            L2_DW(u1.x, 16) L2_DW(u1.y, 20)
            const float sA  = quad_red(cA);            // == (c0+c1)+(c2+c3), all lanes
            const float sB  = quad_red(cB);
            const float mnA = lif_step(sA, bb2A, m2A[b]);
            const float mnB = lif_step(sB, bb2B, m2B[b]);
            if (r == (v & 3)) {                        // one writer lane per quad
                s2r[b][v & 3][(v >> 2)]      = (mnA > 1.0f) ? (unsigned char)1 : (unsigned char)0;
                s2r[b][v & 3][(v >> 2) + 12] = (mnB > 1.0f) ? (unsigned char)1 : (unsigned char)0;
            }
        }
        __syncthreads();   // C: s2r visible

        // ---- layer 3: 96 -> 48, same residue scheme ----
        #pragma unroll
        for (int b = 0; b < NB; ++b) {
            const uint4 u0 = *(const uint4*)&s2r[b][r][0];
            const uint2 u1 = *(const uint2*)&s2r[b][r][16];
            float c = 0.f;
            L3_DW(u0.x,  0) L3_DW(u0.y,  4) L3_DW(u0.z,  8) L3_DW(u0.w, 12)
            L3_DW(u1.x, 16) L3_DW(u1.y, 20)
            const float s  = quad_red(c);
            const float mn = lif_step(s, bb3, m3[b]);
            const size_t obase = ((size_t)t * BATCH + bg0 + b) * H3;
            if (r == 0) out_spk[obase + v] = (mn > 1.0f) ? 1.0f : 0.0f;
            if (r == 1) out_mem[obase + v] = mn;
        }
        // no barrier here: next-t L1 writes s1r, whose readers (L2 of t) all
        // passed barrier C; L3's s2r reads are fenced from next-t L2 writes by
        // barrier B(t+1). xs hazards don't exist (x lives in registers).
    }
}

extern "C" void kernel_launch(void* const* d_in, const int* in_sizes, int n_in,
                              void* d_out, int out_size, void* d_ws, size_t ws_size,
                              hipStream_t stream)
{
    const float* x  = (const float*)d_in[0];
    const float* W1 = (const float*)d_in[1];
    const float* b1 = (const float*)d_in[2];
    const float* W2 = (const float*)d_in[3];
    const float* b2 = (const float*)d_in[4];
    const float* W3 = (const float*)d_in[5];
    const float* b3 = (const float*)d_in[6];
    float* out = (float*)d_out;

    snn_rw<<<dim3(BATCH / NB), dim3(BLOCK), 0, stream>>>(
        x, W1, b1, W2, b2, W3, b3, out);
}